// Round 6
// baseline (951.155 us; speedup 1.0000x reference)
//
#include <hip/hip_runtime.h>
#include <hip/hip_bf16.h>
#include <math.h>

#define D_ 512
#define K_ 8
#define L_ 64
#define Q_ 4096
#define C_ 4096
#define N_ (C_ * K_)   // 32768 rows of P viewed as [N][D]

typedef short short8 __attribute__((ext_vector_type(8)));
typedef float f32x16 __attribute__((ext_vector_type(16)));

static __device__ __forceinline__ void split2(float v, unsigned short& h, unsigned short& l) {
    __hip_bfloat16 hh = __float2bfloat16(v);
    float r = v - __bfloat162float(hh);
    __hip_bfloat16 ll = __float2bfloat16(r);
    h = *reinterpret_cast<unsigned short*>(&hh);
    l = *reinterpret_cast<unsigned short*>(&ll);
}

#define ASYNC_COPY16(gp, lp)                                                        \
    __builtin_amdgcn_global_load_lds((const __attribute__((address_space(1))) void*)(gp), \
                                     (__attribute__((address_space(3))) void*)(lp), \
                                     16, 0, 0)

// ---------------------------------------------------------------------------
// Prep kernels: transposes + fp32 -> bf16 hi/lo splits
// ---------------------------------------------------------------------------
__global__ void transpose_M_split(const float* __restrict__ M,
                                  unsigned short* __restrict__ Mh,
                                  unsigned short* __restrict__ Ml) {
    int idx = blockIdx.x * blockDim.x + threadIdx.x;   // over (K*D)*D, out [k*D+j][i]
    int i = idx & (D_ - 1);
    int n2 = idx >> 9;
    int j = n2 & (D_ - 1);
    int k = n2 >> 9;
    float v = M[((size_t)i * D_ + j) * K_ + k];
    split2(v, Mh[idx], Ml[idx]);
}

__global__ void split_f32(const float* __restrict__ x,
                          unsigned short* __restrict__ hi,
                          unsigned short* __restrict__ lo) {
    int i = blockIdx.x * blockDim.x + threadIdx.x;
    split2(x[i], hi[i], lo[i]);
}

__global__ void transpose_split_classT(const float* __restrict__ x,   // class [C][D]
                                       unsigned short* __restrict__ Th,
                                       unsigned short* __restrict__ Tl) {
    int idx = blockIdx.x * blockDim.x + threadIdx.x;   // out [d][c]
    int c = idx & (C_ - 1);
    int d = idx >> 12;
    float v = x[(size_t)c * D_ + d];
    split2(v, Th[idx], Tl[idx]);
}

// ---------------------------------------------------------------------------
// Pipelined MFMA NT-GEMM core, 32x32x16 bf16 shape, bf16x3 split product.
// Block tile 128x128, BK=32; 4 waves in 2x2, each wave owns a 64x64 tile
// (2x2 sub-tiles of 32x32). A via double-buffered LDS (global_load_lds,
// XOR-swizzled, 2x cross-wave read dup); B direct global->VGPR (2x dup).
// Single barrier per K-iter; next iter's loads issue before the MFMA block.
// ---------------------------------------------------------------------------
#define BM 128
#define BN 128
#define BKK 32

__device__ __forceinline__ void mfma_core(
    const unsigned short* __restrict__ Agh, const unsigned short* __restrict__ Agl,
    const unsigned short* __restrict__ Bgh, const unsigned short* __restrict__ Bgl,
    int lda, int ldb, int kd, int m0, int n0,
    unsigned short (*Ahb)[BM * BKK], unsigned short (*Alb)[BM * BKK],
    f32x16 acc[2][2]) {
    const int tid = threadIdx.x;
    const int lane = tid & 63;
    const int wid = tid >> 6;
    const int wr = (wid >> 1) * 64;
    const int wc = (wid & 1) * 64;
    const int r32 = lane & 31;     // row within a 32-tile
    const int kh = lane >> 5;      // k-half selector

    // B global base: row n0+wc+ni*32+r32, k-offset kh*8 (+ks*16 + j0)
    const unsigned short* bbh = Bgh + (size_t)(n0 + wc + r32) * ldb + kh * 8;
    const unsigned short* bbl = Bgl + (size_t)(n0 + wc + r32) * ldb + kh * 8;

    short8 bh[2][2][2], bl[2][2][2];   // [buf][ni][ks]

    auto stageA = [&](int buf, int j0) {
#pragma unroll
        for (int h = 0; h < 2; ++h) {
            const int i2 = h * 256 + tid;
            const int r = i2 >> 2;
            const int cg = (i2 & 3) ^ ((r >> 1) & 3);
            const int ldsoff = (h * 256 + (tid & ~63)) * 8;
            const size_t go = (size_t)(m0 + r) * lda + j0 + cg * 8;
            ASYNC_COPY16(Agh + go, &Ahb[buf][ldsoff]);
            ASYNC_COPY16(Agl + go, &Alb[buf][ldsoff]);
        }
    };
    auto loadB = [&](int buf, int j0) {
#pragma unroll
        for (int ni = 0; ni < 2; ++ni)
#pragma unroll
            for (int ks = 0; ks < 2; ++ks) {
                const size_t off = (size_t)ni * 32 * ldb + j0 + ks * 16;
                bh[buf][ni][ks] = *(const short8*)(bbh + off);
                bl[buf][ni][ks] = *(const short8*)(bbl + off);
            }
    };

    stageA(0, 0);
    loadB(0, 0);
    __syncthreads();

    const int niter = kd / BKK;
#pragma unroll 2
    for (int it = 0; it < niter; ++it) {
        const int cur = it & 1, nxt = cur ^ 1;
        if (it + 1 < niter) {
            stageA(nxt, (it + 1) * BKK);
            loadB(nxt, (it + 1) * BKK);
        }
#pragma unroll
        for (int ks = 0; ks < 2; ++ks) {
            short8 ah[2], al[2];
#pragma unroll
            for (int mi = 0; mi < 2; ++mi) {
                const int row = wr + mi * 32 + r32;
                const int cg = ((ks * 2 + kh) ^ ((row >> 1) & 3)) * 8;
                ah[mi] = *(const short8*)&Ahb[cur][row * BKK + cg];
                al[mi] = *(const short8*)&Alb[cur][row * BKK + cg];
            }
#pragma unroll
            for (int mi = 0; mi < 2; ++mi)
#pragma unroll
                for (int ni = 0; ni < 2; ++ni) {
                    acc[mi][ni] = __builtin_amdgcn_mfma_f32_32x32x16_bf16(ah[mi], bh[cur][ni][ks], acc[mi][ni], 0, 0, 0);
                    acc[mi][ni] = __builtin_amdgcn_mfma_f32_32x32x16_bf16(ah[mi], bl[cur][ni][ks], acc[mi][ni], 0, 0, 0);
                    acc[mi][ni] = __builtin_amdgcn_mfma_f32_32x32x16_bf16(al[mi], bh[cur][ni][ks], acc[mi][ni], 0, 0, 0);
                }
        }
        __syncthreads();
    }
}

#define CORE_PROLOGUE                                                            \
    __shared__ __attribute__((aligned(16))) unsigned short Ahb[2][BM * BKK];     \
    __shared__ __attribute__((aligned(16))) unsigned short Alb[2][BM * BKK];     \
    const int tid = threadIdx.x;                                                 \
    const int lane = tid & 63;                                                   \
    const int wid = tid >> 6;                                                    \
    const int wr = (wid >> 1) * 64;                                              \
    const int wc = (wid & 1) * 64;                                               \
    const int r32 = lane & 31;                                                   \
    f32x16 acc[2][2] = {};                                                       \
    (void)tid;

// C/D layout for 32x32 MFMA: col = lane&31, row = (reg&3)+8*(reg>>2)+4*(lane>>5)
#define CD_ROW(reg) (((reg) & 3) + 8 * ((reg) >> 2) + 4 * (lane >> 5))

// ---------------------------------------------------------------------------
// gemm_P: Ph/Pl[c][k*D+j] = split( sum_i class[c,i] * M[i,j,k] )
// ---------------------------------------------------------------------------
__launch_bounds__(256, 3)
__global__ void gemm_P_mfma(const unsigned short* __restrict__ Chh,
                            const unsigned short* __restrict__ Cll,
                            const unsigned short* __restrict__ Mh,
                            const unsigned short* __restrict__ Ml,
                            unsigned short* __restrict__ Ph,
                            unsigned short* __restrict__ Pl) {
    CORE_PROLOGUE
    const int n0 = blockIdx.x * BN;   // over K*D
    const int c0 = blockIdx.y * BM;
    mfma_core(Chh, Cll, Mh, Ml, D_, D_, D_, c0, n0, Ahb, Alb, acc);
#pragma unroll
    for (int mi = 0; mi < 2; ++mi)
#pragma unroll
        for (int ni = 0; ni < 2; ++ni)
#pragma unroll
            for (int reg = 0; reg < 16; ++reg) {
                int c = c0 + wr + mi * 32 + CD_ROW(reg);
                int n2 = n0 + wc + ni * 32 + r32;
                size_t o = (size_t)c * (K_ * D_) + n2;
                split2(acc[mi][ni][reg], Ph[o], Pl[o]);
            }
}

// ---------------------------------------------------------------------------
// bilinear: other[q][c] = sb + sum_k sw[k]*relu( sum_j query[q,j]*P[c*8+k][j] )
// Grid is q-fastest: co-resident blocks share one B-panel (L2/L3 locality).
// ---------------------------------------------------------------------------
__launch_bounds__(256, 3)
__global__ void bilinear_mfma(const unsigned short* __restrict__ Qh,
                              const unsigned short* __restrict__ Ql,
                              const unsigned short* __restrict__ Ph,
                              const unsigned short* __restrict__ Pl,
                              const float* __restrict__ sw,
                              const float* __restrict__ sb,
                              float* __restrict__ other) {
    CORE_PROLOGUE
    const int q0 = blockIdx.x * BM;   // q-fastest
    const int n0 = blockIdx.y * BN;   // over N = C*K
    mfma_core(Qh, Ql, Ph, Pl, D_, D_, D_, q0, n0, Ahb, Alb, acc);
    const float wk = sw[lane & 7];
    const float bias = sb[0];
#pragma unroll
    for (int mi = 0; mi < 2; ++mi)
#pragma unroll
        for (int ni = 0; ni < 2; ++ni)
#pragma unroll
            for (int reg = 0; reg < 16; ++reg) {
                float v = wk * fmaxf(acc[mi][ni][reg], 0.f);
                v += __shfl_xor(v, 1);
                v += __shfl_xor(v, 2);
                v += __shfl_xor(v, 4);
                if ((lane & 7) == 0) {
                    int q = q0 + wr + mi * 32 + CD_ROW(reg);
                    int c = (n0 + wc + ni * 32 + r32) >> 3;
                    other[(size_t)q * C_ + c] = v + bias;
                }
            }
}

// ---------------------------------------------------------------------------
// gemm_qf (split-K=4 over grid.z): qfp[z][q][d] = sum_{c in quarter} probs*classT
// ---------------------------------------------------------------------------
__launch_bounds__(256, 3)
__global__ void gemm_qf_mfma(const unsigned short* __restrict__ Sh,
                             const unsigned short* __restrict__ Sl,
                             const unsigned short* __restrict__ Th,
                             const unsigned short* __restrict__ Tl,
                             float* __restrict__ qfp_base) {
    CORE_PROLOGUE
    const int n0 = blockIdx.x * BN;   // over D
    const int q0 = blockIdx.y * BM;
    const int zoff = blockIdx.z * (C_ / 4);
    float* qfp = qfp_base + (size_t)blockIdx.z * Q_ * D_;
    mfma_core(Sh + zoff, Sl + zoff, Th + zoff, Tl + zoff,
              C_, C_, C_ / 4, q0, n0, Ahb, Alb, acc);
#pragma unroll
    for (int mi = 0; mi < 2; ++mi)
#pragma unroll
        for (int ni = 0; ni < 2; ++ni)
#pragma unroll
            for (int reg = 0; reg < 16; ++reg) {
                int q = q0 + wr + mi * 32 + CD_ROW(reg);
                int d = n0 + wc + ni * 32 + r32;
                qfp[(size_t)q * D_ + d] = acc[mi][ni][reg];
            }
}

// ---------------------------------------------------------------------------
// Softmax over C per row; emits probs as split bf16 hi/lo. Row in registers.
// ---------------------------------------------------------------------------
__launch_bounds__(256)
__global__ void softmax_split(const float* __restrict__ other,
                              unsigned short* __restrict__ Sh,
                              unsigned short* __restrict__ Sl) {
    const int q = blockIdx.x;
    const float* row = other + (size_t)q * C_;
    const int tid = threadIdx.x;
    __shared__ float red[4];
    float v[16];
    float m = -1e30f;
#pragma unroll
    for (int it = 0; it < 16; ++it) {
        v[it] = row[tid + it * 256];
        m = fmaxf(m, v[it]);
    }
#pragma unroll
    for (int off = 32; off; off >>= 1) m = fmaxf(m, __shfl_down(m, off));
    if ((tid & 63) == 0) red[tid >> 6] = m;
    __syncthreads();
    m = fmaxf(fmaxf(red[0], red[1]), fmaxf(red[2], red[3]));
    __syncthreads();
    float s = 0.f;
#pragma unroll
    for (int it = 0; it < 16; ++it) {
        v[it] = __expf(v[it] - m);
        s += v[it];
    }
#pragma unroll
    for (int off = 32; off; off >>= 1) s += __shfl_down(s, off);
    if ((tid & 63) == 0) red[tid >> 6] = s;
    __syncthreads();
    const float inv = 1.f / (red[0] + red[1] + red[2] + red[3]);
#pragma unroll
    for (int it = 0; it < 16; ++it) {
        size_t o = (size_t)q * C_ + tid + it * 256;
        split2(v[it] * inv, Sh[o], Sl[o]);
    }
}

// ---------------------------------------------------------------------------
// hash[q][l] = tanh( sum_d (sum_z qfp[z] + query)[q][d]*hash_w[l][d] + hb[l] )
// ---------------------------------------------------------------------------
__launch_bounds__(256)
__global__ void hash_kernel(const float* __restrict__ qfp_base,
                            const float* __restrict__ Qv,
                            const float* __restrict__ hw,
                            const float* __restrict__ hb,
                            float* __restrict__ out) {
    __shared__ float sqf[4 * D_];
    const int q0 = blockIdx.x * 4;
    const int tid = threadIdx.x;
    {
        const float4* s0 = (const float4*)&qfp_base[(size_t)q0 * D_];
        const float4* s1 = (const float4*)&qfp_base[(size_t)Q_ * D_ + q0 * D_];
        const float4* s2 = (const float4*)&qfp_base[(size_t)2 * Q_ * D_ + q0 * D_];
        const float4* s3 = (const float4*)&qfp_base[(size_t)3 * Q_ * D_ + q0 * D_];
        const float4* s4 = (const float4*)&Qv[(size_t)q0 * D_];
        float4* dst = (float4*)sqf;
#pragma unroll
        for (int it = 0; it < 2; ++it) {
            int i = tid + it * 256;
            float4 a = s0[i], b = s1[i], c = s2[i], d = s3[i], e = s4[i];
            float4 o = {a.x + b.x + c.x + d.x + e.x, a.y + b.y + c.y + d.y + e.y,
                        a.z + b.z + c.z + d.z + e.z, a.w + b.w + c.w + d.w + e.w};
            dst[i] = o;
        }
    }
    __syncthreads();
    const int l = tid % L_;
    const int qi = tid / L_;
    float s = hb[l];
    const float* wrow = &hw[(size_t)l * D_];
    const float* xrow = &sqf[qi * D_];
#pragma unroll 4
    for (int d = 0; d < D_; d += 4) {
        float4 w4 = *(const float4*)&wrow[d];
        float4 x4 = *(const float4*)&xrow[d];
        s += x4.x * w4.x + x4.y * w4.y + x4.z * w4.z + x4.w * w4.w;
    }
    out[(size_t)(q0 + qi) * L_ + l] = tanhf(s);
}

// ---------------------------------------------------------------------------
extern "C" void kernel_launch(void* const* d_in, const int* in_sizes, int n_in,
                              void* d_out, int out_size, void* d_ws, size_t ws_size,
                              hipStream_t stream) {
    const float* class_v = (const float*)d_in[0];
    const float* query_v = (const float*)d_in[1];
    const float* M       = (const float*)d_in[2];
    const float* score_w = (const float*)d_in[3];
    const float* score_b = (const float*)d_in[4];
    const float* hash_w  = (const float*)d_in[5];
    const float* hash_b  = (const float*)d_in[6];
    float* out = (float*)d_out;

    // Workspace (142.6 MB, same footprint as rounds 1-5):
    //  [0,     33.5M)  Ph            -> Sh (probs hi) after softmax
    //  [33.5M, 67M)    Pl            -> Sl (probs lo)
    //  [67M,   134.2M) other (fp32 Q*C logits)
    //                  prep aliases (dead once bilinear writes other):
    //                    Mh/Ml at +0/+4.2M, Ch/Cl at +8.4M/+12.6M
    //                  post-softmax alias: qfp[4] at +0 (4 x 8.4M fp32)
    //  [134.2M,142.6M) scratch: Qh/Ql (bf16)  -> Th/Tl (classT) after bilinear
    char* base = (char*)d_ws;
    unsigned short* Ph = (unsigned short*)base;
    unsigned short* Pl = (unsigned short*)(base + (size_t)33554432);
    char* oreg          = base + (size_t)67108864;
    float* other        = (float*)oreg;
    unsigned short* Mh  = (unsigned short*)oreg;
    unsigned short* Ml  = (unsigned short*)(oreg + (size_t)4194304);
    unsigned short* Chh = (unsigned short*)(oreg + (size_t)8388608);
    unsigned short* Cll = (unsigned short*)(oreg + (size_t)12582912);
    float* qfp          = (float*)oreg;
    char* scratch = base + (size_t)134217728;
    unsigned short* Qh = (unsigned short*)scratch;
    unsigned short* Ql = (unsigned short*)(scratch + (size_t)4194304);
    unsigned short* Th = (unsigned short*)scratch;
    unsigned short* Tl = (unsigned short*)(scratch + (size_t)4194304);
    unsigned short* Sh = Ph;
    unsigned short* Sl = Pl;

    transpose_M_split<<<(K_ * D_ * D_) / 256, 256, 0, stream>>>(M, Mh, Ml);
    split_f32<<<(C_ * D_) / 256, 256, 0, stream>>>(class_v, Chh, Cll);
    split_f32<<<(Q_ * D_) / 256, 256, 0, stream>>>(query_v, Qh, Ql);
    gemm_P_mfma<<<dim3((K_ * D_) / BN, C_ / BM), 256, 0, stream>>>(Chh, Cll, Mh, Ml, Ph, Pl);
    bilinear_mfma<<<dim3(Q_ / BM, N_ / BN), 256, 0, stream>>>(Qh, Ql, Ph, Pl,
                                                              score_w, score_b, other);
    softmax_split<<<Q_, 256, 0, stream>>>(other, Sh, Sl);
    transpose_split_classT<<<(C_ * D_) / 256, 256, 0, stream>>>(class_v, Th, Tl);
    gemm_qf_mfma<<<dim3(D_ / BN, Q_ / BM, 4), 256, 0, stream>>>(Sh, Sl, Th, Tl, qfp);
    hash_kernel<<<Q_ / 4, 256, 0, stream>>>(qfp, query_v, hash_w, hash_b, out);
}